// Round 4
// baseline (2509.282 us; speedup 1.0000x reference)
//
#include <hip/hip_runtime.h>
#include <math.h>

#define EMBED 256
#define ACTD  7
#define MEM   200
#define STOCH 30
#define HIDD  200
#define T_    256
#define B_    512
#define EAIN  263      // EMBED + ACTD
#define G3    600      // 3*MEM
#define K2EA  132      // ceil(EAIN/2)
#define K2IH  100      // HIDD/2
#define RP    36       // padded row length (dwords) for LDS tiles

typedef unsigned int uint32;
typedef _Float16 h2v __attribute__((ext_vector_type(2)));

// ---------- math helpers ----------
__device__ __forceinline__ float eluf(float x)  { return x > 0.f ? x : expm1f(x); }
__device__ __forceinline__ float sigmf(float x) { return 1.f / (1.f + __expf(-x)); }
__device__ __forceinline__ float splusf(float x){ return fmaxf(x, 0.f) + log1pf(__expf(-fabsf(x))); }

__device__ __forceinline__ uint32 packh2(float a, float b) {
#if __has_builtin(__builtin_amdgcn_cvt_pkrtz)
    auto h = __builtin_amdgcn_cvt_pkrtz(a, b);   // __fp16 ext_vector(2)
    return __builtin_bit_cast(uint32, h);
#else
    h2v h; h.x = (_Float16)a; h.y = (_Float16)b;
    return __builtin_bit_cast(uint32, h);
#endif
}

__device__ __forceinline__ float dot2f(uint32 a, uint32 b, float acc) {
#if __has_builtin(__builtin_amdgcn_fdot2)
    return __builtin_amdgcn_fdot2(__builtin_bit_cast(h2v, a),
                                  __builtin_bit_cast(h2v, b), acc, false);
#else
    h2v ha = __builtin_bit_cast(h2v, a), hb = __builtin_bit_cast(h2v, b);
    return acc + (float)ha.x * (float)hb.x + (float)ha.y * (float)hb.y;
#endif
}

// ---------- reset dtype detection ----------
__global__ void detect_kernel(const unsigned char* __restrict__ p, int n, int* __restrict__ flags)
{
    __shared__ int s_mis, s_gt1;
    if (threadIdx.x == 0) { s_mis = 0; s_gt1 = 0; }
    __syncthreads();
    int mis = 0, gt1 = 0;
    for (int i = threadIdx.x; i < n; i += blockDim.x) {
        unsigned char v = p[i];
        if (v) {
            if (i & 3) mis = 1;
            if (v > 1) gt1 = 1;
        }
    }
    if (mis) atomicOr(&s_mis, 1);
    if (gt1) atomicOr(&s_gt1, 1);
    __syncthreads();
    if (threadIdx.x == 0) flags[0] = s_mis ? (s_gt1 ? 2 : 1) : 0;
}

__device__ __forceinline__ bool resetval(const unsigned char* __restrict__ p, int mode, int idx)
{
    if (mode == 0) return ((const int*)p)[idx] != 0;
    if (mode == 1) return p[idx] != 0;
    return ((const float*)p)[idx] != 0.f;
}

// ---------- weight packing: src[K][C] f32 -> dst[ceil(K/2)][C] f16x2 ----------
__global__ void pack_kernel(const float* __restrict__ src, uint32* __restrict__ dst, int K, int C)
{
    int idx = blockIdx.x * blockDim.x + threadIdx.x;
    int K2 = (K + 1) >> 1;
    if (idx < K2 * C) {
        int k2 = idx / C, c = idx % C;
        float a = src[(size_t)(2 * k2) * C + c];
        float b = (2 * k2 + 1 < K) ? src[(size_t)(2 * k2 + 1) * C + c] : 0.f;
        dst[idx] = packh2(a, b);
    }
}

// ---------- phase A: gi = elu([e,a]@W_ea+b_ea)@W_ih + b_ih ----------
#define GI_ROWS 32
#define GI_THREADS 640

__global__ __launch_bounds__(GI_THREADS)
void gi2_kernel(const float* __restrict__ embed, const float* __restrict__ action,
                const uint32* __restrict__ Wea_pk, const float* __restrict__ b_ea,
                const uint32* __restrict__ Wih_pk, const float* __restrict__ b_ih,
                float* __restrict__ gi, int row_base)
{
    __shared__ __align__(16) uint32 Epk[K2EA][RP];   // packed E, [k2][r]
    __shared__ __align__(16) uint32 eapk[K2IH][RP];  // packed elu(ea), [c2][r]

    const int tid = threadIdx.x;
    const int rel0 = blockIdx.x * GI_ROWS;
    const int rg0  = row_base + rel0;

    // stage E = concat(embed, action) as packed f16 pairs over k
    for (int idx = tid; idx < GI_ROWS * K2EA; idx += GI_THREADS) {
        int r = idx / K2EA, k2 = idx % K2EA;
        size_t rg = (size_t)(rg0 + r);
        float a, b;
        if (k2 < EMBED / 2) {
            const float2 v = *(const float2*)&embed[rg * EMBED + 2 * k2];
            a = v.x; b = v.y;
        } else {
            int k = 2 * k2 - EMBED;                 // 0..6 in action
            a = action[rg * ACTD + k];
            b = (k + 1 < ACTD) ? action[rg * ACTD + k + 1] : 0.f;
        }
        Epk[k2][r] = packh2(a, b);
    }
    __syncthreads();

    // ea phase: 400 threads, (c<200, g<2), 16 rows each
    if (tid < 400) {
        const int c = tid % 200;
        const int g = tid / 200;
        float acc[16];
        const float bv = b_ea[c];
        #pragma unroll
        for (int r = 0; r < 16; r++) acc[r] = bv;
        for (int k2 = 0; k2 < K2EA; k2++) {
            uint32 w = Wea_pk[k2 * 200 + c];
            #pragma unroll
            for (int q = 0; q < 4; q++) {
                const uint4 e4 = *(const uint4*)&Epk[k2][g * 16 + q * 4];
                acc[q * 4 + 0] = dot2f(w, e4.x, acc[q * 4 + 0]);
                acc[q * 4 + 1] = dot2f(w, e4.y, acc[q * 4 + 1]);
                acc[q * 4 + 2] = dot2f(w, e4.z, acc[q * 4 + 2]);
                acc[q * 4 + 3] = dot2f(w, e4.w, acc[q * 4 + 3]);
            }
        }
        // elu, then pack pairs over c via lane shuffle (lane parity == c parity)
        uint32 packed[16];
        #pragma unroll
        for (int r = 0; r < 16; r++) {
            float v = eluf(acc[r]);
            float p = __shfl_xor(v, 1);
            packed[r] = packh2(v, p);
        }
        if ((c & 1) == 0) {
            #pragma unroll
            for (int q = 0; q < 4; q++) {
                uint4 u;
                u.x = packed[q * 4 + 0]; u.y = packed[q * 4 + 1];
                u.z = packed[q * 4 + 2]; u.w = packed[q * 4 + 3];
                *(uint4*)&eapk[c >> 1][g * 16 + q * 4] = u;
            }
        }
    }
    __syncthreads();

    // gi phase: 600 threads, col c, 32 rows each
    if (tid < G3) {
        const int c = tid;
        float acc[GI_ROWS];
        const float bv = b_ih[c];
        #pragma unroll
        for (int r = 0; r < GI_ROWS; r++) acc[r] = bv;
        for (int k2 = 0; k2 < K2IH; k2++) {
            uint32 w = Wih_pk[k2 * G3 + c];
            #pragma unroll
            for (int q = 0; q < 8; q++) {
                const uint4 e4 = *(const uint4*)&eapk[k2][q * 4];
                acc[q * 4 + 0] = dot2f(w, e4.x, acc[q * 4 + 0]);
                acc[q * 4 + 1] = dot2f(w, e4.y, acc[q * 4 + 1]);
                acc[q * 4 + 2] = dot2f(w, e4.z, acc[q * 4 + 2]);
                acc[q * 4 + 3] = dot2f(w, e4.w, acc[q * 4 + 3]);
            }
        }
        #pragma unroll
        for (int r = 0; r < GI_ROWS; r++)
            gi[(size_t)(rel0 + r) * G3 + c] = acc[r];
    }
}

// ---------- phase B: sequential GRU recurrence, 1 batch row per block ----------
#define RB_THREADS 640

__global__ __launch_bounds__(RB_THREADS, 5)   // 5 waves/SIMD = 2 blocks/CU
void recur3_kernel(const float* __restrict__ gi, const uint32* __restrict__ Whh_pk,
                   const float* __restrict__ b_hh, const float* __restrict__ in_state,
                   const unsigned char* __restrict__ reset_raw, const int* __restrict__ flags,
                   float* __restrict__ out_states, float* __restrict__ h_buf,
                   int t0, int t1, int first)
{
    __shared__ __align__(16) uint32 hpk[K2IH];   // packed f16 h (100 dwords)
    __shared__ __align__(16) float  gh_s[G3];

    const int tid = threadIdx.x;
    const int bg  = blockIdx.x;                  // one batch row per block
    const int mode = flags[0];

    // thread j<600 owns packed column j of W_hh: 100 VGPRs
    uint32 wpk[K2IH];
    float bh = 0.f;
    if (tid < G3) {
        bh = b_hh[tid];
        #pragma unroll
        for (int j = 0; j < K2IH; j++) wpk[j] = Whh_pk[j * G3 + tid];
    }

    float h_old = 0.f;
    if (tid < MEM) {
        float h;
        if (first) {
            h = in_state[bg * MEM + tid];
            if (resetval(reset_raw, mode, bg)) h = 0.f;
        } else {
            h = h_buf[bg * MEM + tid];
        }
        h_old = h;
        float p = __shfl_xor(h, 1);
        if ((tid & 1) == 0) hpk[tid >> 1] = packh2(h, p);
    }
    __syncthreads();

    for (int t = t0; t < t1; ++t) {
        // prefetch this step's gi + next reset (hides under the dot loop)
        float gr = 0.f, gz = 0.f, gn = 0.f;
        bool rnext = false;
        if (tid < MEM) {
            const float* gir = gi + ((size_t)(t - t0) * B_ + bg) * G3;
            gr = gir[tid]; gz = gir[MEM + tid]; gn = gir[2 * MEM + tid];
            if (t + 1 < T_) rnext = resetval(reset_raw, mode, (t + 1) * B_ + bg);
        }

        // gh = h @ W_hh + b_hh via f16 dot2, 4 independent chains
        if (tid < G3) {
            float a0 = 0.f, a1 = 0.f, a2 = 0.f, a3 = 0.f;
            #pragma unroll
            for (int j4 = 0; j4 < K2IH / 4; j4++) {
                const uint4 p0 = *(const uint4*)&hpk[j4 * 4];
                a0 = dot2f(wpk[j4 * 4 + 0], p0.x, a0);
                a1 = dot2f(wpk[j4 * 4 + 1], p0.y, a1);
                a2 = dot2f(wpk[j4 * 4 + 2], p0.z, a2);
                a3 = dot2f(wpk[j4 * 4 + 3], p0.w, a3);
            }
            gh_s[tid] = ((a0 + a1) + (a2 + a3)) + bh;
        }
        __syncthreads();

        // gates + state update
        if (tid < MEM) {
            float gh_r = gh_s[tid], gh_z = gh_s[MEM + tid], gh_n = gh_s[2 * MEM + tid];
            float rg = sigmf(gr + gh_r);
            float zg = sigmf(gz + gh_z);
            float x  = gn + rg * gh_n;
            x = fminf(fmaxf(x, -30.f), 30.f);
            float e2 = __expf(2.f * x);
            float ng = (e2 - 1.f) / (e2 + 1.f);
            float hn = (1.f - zg) * ng + zg * h_old;
            out_states[((size_t)t * B_ + bg) * MEM + tid] = hn;
            if (rnext) hn = 0.f;
            h_old = hn;
            float p = __shfl_xor(hn, 1);
            if ((tid & 1) == 0) hpk[tid >> 1] = packh2(hn, p);
        }
        __syncthreads();
    }

    if (tid < MEM) h_buf[bg * MEM + tid] = h_old;
}

// ---------- phase C: post MLP over all states ----------
#define PC_THREADS 256
#define PC_ROWS 32

__global__ __launch_bounds__(PC_THREADS)
void post2_kernel(const float* __restrict__ states, const uint32* __restrict__ Wp1_pk,
                  const float* __restrict__ bp1, const uint32* __restrict__ Wp2_pk,
                  const float* __restrict__ bp2, float* __restrict__ posts)
{
    __shared__ __align__(16) uint32 hp[K2IH][RP];   // packed states [k2][r]
    __shared__ __align__(16) uint32 mp[K2IH][RP];   // packed elu(mid) [c2][r]

    const int tid = threadIdx.x;
    const size_t rg0 = (size_t)blockIdx.x * PC_ROWS;

    for (int idx = tid; idx < PC_ROWS * K2IH; idx += PC_THREADS) {
        int r = idx / K2IH, k2 = idx % K2IH;
        const float2 v = *(const float2*)&states[(rg0 + r) * MEM + 2 * k2];
        hp[k2][r] = packh2(v.x, v.y);
    }
    __syncthreads();

    // mid = elu(h@Wp1+bp1): 200 threads, 32 rows
    if (tid < MEM) {
        const int c = tid;
        float acc[PC_ROWS];
        const float bv = bp1[c];
        #pragma unroll
        for (int r = 0; r < PC_ROWS; r++) acc[r] = bv;
        for (int k2 = 0; k2 < K2IH; k2++) {
            uint32 w = Wp1_pk[k2 * MEM + c];
            #pragma unroll
            for (int q = 0; q < 8; q++) {
                const uint4 e4 = *(const uint4*)&hp[k2][q * 4];
                acc[q * 4 + 0] = dot2f(w, e4.x, acc[q * 4 + 0]);
                acc[q * 4 + 1] = dot2f(w, e4.y, acc[q * 4 + 1]);
                acc[q * 4 + 2] = dot2f(w, e4.z, acc[q * 4 + 2]);
                acc[q * 4 + 3] = dot2f(w, e4.w, acc[q * 4 + 3]);
            }
        }
        uint32 packed[PC_ROWS];
        #pragma unroll
        for (int r = 0; r < PC_ROWS; r++) {
            float v = eluf(acc[r]);
            float p = __shfl_xor(v, 1);
            packed[r] = packh2(v, p);
        }
        if ((c & 1) == 0) {
            #pragma unroll
            for (int q = 0; q < 8; q++) {
                uint4 u;
                u.x = packed[q * 4 + 0]; u.y = packed[q * 4 + 1];
                u.z = packed[q * 4 + 2]; u.w = packed[q * 4 + 3];
                *(uint4*)&mp[c >> 1][q * 4] = u;
            }
        }
    }
    __syncthreads();

    // post = mid@Wp2+bp2 (+ mean/std transform): 240 threads = (c<60, q<4), 8 rows each
    if (tid < 240) {
        const int c = tid % 60;
        const int q = tid / 60;
        float acc[8];
        const float bv = bp2[c];
        #pragma unroll
        for (int r = 0; r < 8; r++) acc[r] = bv;
        for (int k2 = 0; k2 < K2IH; k2++) {
            uint32 w = Wp2_pk[k2 * 60 + c];
            const uint4 a4 = *(const uint4*)&mp[k2][q * 8 + 0];
            const uint4 b4 = *(const uint4*)&mp[k2][q * 8 + 4];
            acc[0] = dot2f(w, a4.x, acc[0]);
            acc[1] = dot2f(w, a4.y, acc[1]);
            acc[2] = dot2f(w, a4.z, acc[2]);
            acc[3] = dot2f(w, a4.w, acc[3]);
            acc[4] = dot2f(w, b4.x, acc[4]);
            acc[5] = dot2f(w, b4.y, acc[5]);
            acc[6] = dot2f(w, b4.z, acc[6]);
            acc[7] = dot2f(w, b4.w, acc[7]);
        }
        #pragma unroll
        for (int r8 = 0; r8 < 8; r8++) {
            size_t rg = rg0 + q * 8 + r8;
            float v = acc[r8];
            posts[rg * 60 + c] = (c < 30) ? v : (splusf(v) + 0.1f);
        }
    }
}

// ---------- sample = mean + std*noise from posts[T-1] ----------
__global__ void sample_kernel(const float* __restrict__ posts_last,
                              const float* __restrict__ noise, float* __restrict__ out)
{
    int idx = blockIdx.x * blockDim.x + threadIdx.x;
    if (idx < B_ * STOCH) {
        int b = idx / STOCH, s = idx % STOCH;
        float mean = posts_last[b * 60 + s];
        float stdv = posts_last[b * 60 + 30 + s];
        out[idx] = mean + stdv * noise[idx];
    }
}

extern "C" void kernel_launch(void* const* d_in, const int* in_sizes, int n_in,
                              void* d_out, int out_size, void* d_ws, size_t ws_size,
                              hipStream_t stream)
{
    const float* embed   = (const float*)d_in[0];
    const float* action  = (const float*)d_in[1];
    const unsigned char* reset = (const unsigned char*)d_in[2];
    const float* in_state = (const float*)d_in[3];
    const float* noise   = (const float*)d_in[4];
    const float* W_ea = (const float*)d_in[5];
    const float* b_ea = (const float*)d_in[6];
    const float* W_ih = (const float*)d_in[7];
    const float* b_ih = (const float*)d_in[8];
    const float* W_hh = (const float*)d_in[9];
    const float* b_hh = (const float*)d_in[10];
    const float* Wp1  = (const float*)d_in[11];
    const float* bp1  = (const float*)d_in[12];
    const float* Wp2  = (const float*)d_in[13];
    const float* bp2  = (const float*)d_in[14];

    float* out_sample = (float*)d_out;
    float* out_states = out_sample + (size_t)B_ * STOCH;
    float* out_posts  = out_states + (size_t)T_ * B_ * MEM;

    char* ws = (char*)d_ws;
    size_t off = 0;
    int*    flags  = (int*)(ws + off);      off += 256;
    float*  h_buf  = (float*)(ws + off);    off += (size_t)B_ * MEM * 4;        // 409600
    uint32* Wea_pk = (uint32*)(ws + off);   off += (size_t)K2EA * 200 * 4;      // 105600
    uint32* Wih_pk = (uint32*)(ws + off);   off += (size_t)K2IH * G3 * 4;       // 240000
    uint32* Whh_pk = (uint32*)(ws + off);   off += (size_t)K2IH * G3 * 4;       // 240000
    uint32* Wp1_pk = (uint32*)(ws + off);   off += (size_t)K2IH * MEM * 4;      // 80000
    uint32* Wp2_pk = (uint32*)(ws + off);   off += (size_t)K2IH * 60 * 4;       // 24000
    float*  gi_buf = (float*)(ws + off);

    const size_t per_t = (size_t)B_ * G3 * 4;
    size_t avail = (ws_size > off) ? (ws_size - off) : 0;
    int maxT = (int)(avail / per_t);
    int chunkT = 1;
    while (chunkT * 2 <= maxT && chunkT < T_) chunkT *= 2;

    detect_kernel<<<1, 1024, 0, stream>>>(reset, T_ * B_, flags);
    pack_kernel<<<(K2EA * 200 + 255) / 256, 256, 0, stream>>>(W_ea, Wea_pk, EAIN, 200);
    pack_kernel<<<(K2IH * G3 + 255) / 256, 256, 0, stream>>>(W_ih, Wih_pk, HIDD, G3);
    pack_kernel<<<(K2IH * G3 + 255) / 256, 256, 0, stream>>>(W_hh, Whh_pk, MEM, G3);
    pack_kernel<<<(K2IH * MEM + 255) / 256, 256, 0, stream>>>(Wp1, Wp1_pk, MEM, MEM);
    pack_kernel<<<(K2IH * 60 + 255) / 256, 256, 0, stream>>>(Wp2, Wp2_pk, MEM, 60);

    for (int t0 = 0; t0 < T_; t0 += chunkT) {
        int rows = chunkT * B_;
        gi2_kernel<<<rows / GI_ROWS, GI_THREADS, 0, stream>>>(
            embed, action, Wea_pk, b_ea, Wih_pk, b_ih, gi_buf, t0 * B_);
        recur3_kernel<<<B_, RB_THREADS, 0, stream>>>(
            gi_buf, Whh_pk, b_hh, in_state, reset, flags,
            out_states, h_buf, t0, t0 + chunkT, (t0 == 0) ? 1 : 0);
    }

    post2_kernel<<<(T_ * B_) / PC_ROWS, PC_THREADS, 0, stream>>>(
        out_states, Wp1_pk, bp1, Wp2_pk, bp2, out_posts);

    sample_kernel<<<(B_ * STOCH + 255) / 256, 256, 0, stream>>>(
        out_posts + (size_t)(T_ - 1) * B_ * 60, noise, out_sample);
}

// Round 5
// 1485.166 us; speedup vs baseline: 1.6896x; 1.6896x over previous
//
#include <hip/hip_runtime.h>
#include <math.h>

#define EMBED 256
#define ACTD  7
#define MEM   200
#define STOCH 30
#define HIDD  200
#define T_    256
#define B_    512
#define EAIN  263      // EMBED + ACTD
#define G3    600      // 3*MEM
#define K2EA  132      // ceil(EAIN/2)
#define K2IH  100      // HIDD/2
#define RP    36       // padded row length (dwords) for LDS tiles

typedef unsigned int uint32;
typedef _Float16 h2v  __attribute__((ext_vector_type(2)));
typedef _Float16 f16x8 __attribute__((ext_vector_type(8)));
typedef float    f32x4 __attribute__((ext_vector_type(4)));

// ---------- math helpers ----------
__device__ __forceinline__ float eluf(float x)  { return x > 0.f ? x : expm1f(x); }
__device__ __forceinline__ float sigmf(float x) { return 1.f / (1.f + __expf(-x)); }
__device__ __forceinline__ float splusf(float x){ return fmaxf(x, 0.f) + log1pf(__expf(-fabsf(x))); }

__device__ __forceinline__ uint32 packh2(float a, float b) {
#if __has_builtin(__builtin_amdgcn_cvt_pkrtz)
    auto h = __builtin_amdgcn_cvt_pkrtz(a, b);   // __fp16 ext_vector(2)
    return __builtin_bit_cast(uint32, h);
#else
    h2v h; h.x = (_Float16)a; h.y = (_Float16)b;
    return __builtin_bit_cast(uint32, h);
#endif
}

__device__ __forceinline__ float dot2f(uint32 a, uint32 b, float acc) {
#if __has_builtin(__builtin_amdgcn_fdot2)
    return __builtin_amdgcn_fdot2(__builtin_bit_cast(h2v, a),
                                  __builtin_bit_cast(h2v, b), acc, false);
#else
    h2v ha = __builtin_bit_cast(h2v, a), hb = __builtin_bit_cast(h2v, b);
    return acc + (float)ha.x * (float)hb.x + (float)ha.y * (float)hb.y;
#endif
}

// ---------- reset dtype detection ----------
__global__ void detect_kernel(const unsigned char* __restrict__ p, int n, int* __restrict__ flags)
{
    __shared__ int s_mis, s_gt1;
    if (threadIdx.x == 0) { s_mis = 0; s_gt1 = 0; }
    __syncthreads();
    int mis = 0, gt1 = 0;
    for (int i = threadIdx.x; i < n; i += blockDim.x) {
        unsigned char v = p[i];
        if (v) {
            if (i & 3) mis = 1;
            if (v > 1) gt1 = 1;
        }
    }
    if (mis) atomicOr(&s_mis, 1);
    if (gt1) atomicOr(&s_gt1, 1);
    __syncthreads();
    if (threadIdx.x == 0) flags[0] = s_mis ? (s_gt1 ? 2 : 1) : 0;
}

__device__ __forceinline__ bool resetval(const unsigned char* __restrict__ p, int mode, int idx)
{
    if (mode == 0) return ((const int*)p)[idx] != 0;
    if (mode == 1) return p[idx] != 0;
    return ((const float*)p)[idx] != 0.f;
}

// ---------- weight packing: src[K][C] f32 -> dst[ceil(K/2)][C] f16x2 ----------
__global__ void pack_kernel(const float* __restrict__ src, uint32* __restrict__ dst, int K, int C)
{
    int idx = blockIdx.x * blockDim.x + threadIdx.x;
    int K2 = (K + 1) >> 1;
    if (idx < K2 * C) {
        int k2 = idx / C, c = idx % C;
        float a = src[(size_t)(2 * k2) * C + c];
        float b = (2 * k2 + 1 < K) ? src[(size_t)(2 * k2 + 1) * C + c] : 0.f;
        dst[idx] = packh2(a, b);
    }
}

// ---------- W_hh transpose-pack for MFMA B-frags: dst[608][112] u32 = f16 pair over k ----------
__global__ void packWT_kernel(const float* __restrict__ W, uint32* __restrict__ dst)
{
    int idx = blockIdx.x * blockDim.x + threadIdx.x;
    if (idx < 608 * 112) {
        int j = idx / 112, k2 = idx % 112;
        float a = (j < G3 && 2 * k2     < MEM) ? W[(size_t)(2 * k2)     * G3 + j] : 0.f;
        float b = (j < G3 && 2 * k2 + 1 < MEM) ? W[(size_t)(2 * k2 + 1) * G3 + j] : 0.f;
        dst[idx] = packh2(a, b);
    }
}

// ---------- phase A: gi = elu([e,a]@W_ea+b_ea)@W_ih + b_ih  (output packed f16) ----------
#define GI_ROWS 32
#define GI_THREADS 640

__global__ __launch_bounds__(GI_THREADS)
void gi2_kernel(const float* __restrict__ embed, const float* __restrict__ action,
                const uint32* __restrict__ Wea_pk, const float* __restrict__ b_ea,
                const uint32* __restrict__ Wih_pk, const float* __restrict__ b_ih,
                uint32* __restrict__ gi_pk, int row_base)
{
    __shared__ __align__(16) uint32 Epk[K2EA][RP];   // packed E, [k2][r]
    __shared__ __align__(16) uint32 eapk[K2IH][RP];  // packed elu(ea), [c2][r]

    const int tid = threadIdx.x;
    const int rel0 = blockIdx.x * GI_ROWS;
    const int rg0  = row_base + rel0;

    for (int idx = tid; idx < GI_ROWS * K2EA; idx += GI_THREADS) {
        int r = idx / K2EA, k2 = idx % K2EA;
        size_t rg = (size_t)(rg0 + r);
        float a, b;
        if (k2 < EMBED / 2) {
            const float2 v = *(const float2*)&embed[rg * EMBED + 2 * k2];
            a = v.x; b = v.y;
        } else {
            int k = 2 * k2 - EMBED;
            a = action[rg * ACTD + k];
            b = (k + 1 < ACTD) ? action[rg * ACTD + k + 1] : 0.f;
        }
        Epk[k2][r] = packh2(a, b);
    }
    __syncthreads();

    if (tid < 400) {
        const int c = tid % 200;
        const int g = tid / 200;
        float acc[16];
        const float bv = b_ea[c];
        #pragma unroll
        for (int r = 0; r < 16; r++) acc[r] = bv;
        for (int k2 = 0; k2 < K2EA; k2++) {
            uint32 w = Wea_pk[k2 * 200 + c];
            #pragma unroll
            for (int q = 0; q < 4; q++) {
                const uint4 e4 = *(const uint4*)&Epk[k2][g * 16 + q * 4];
                acc[q * 4 + 0] = dot2f(w, e4.x, acc[q * 4 + 0]);
                acc[q * 4 + 1] = dot2f(w, e4.y, acc[q * 4 + 1]);
                acc[q * 4 + 2] = dot2f(w, e4.z, acc[q * 4 + 2]);
                acc[q * 4 + 3] = dot2f(w, e4.w, acc[q * 4 + 3]);
            }
        }
        uint32 packed[16];
        #pragma unroll
        for (int r = 0; r < 16; r++) {
            float v = eluf(acc[r]);
            float p = __shfl_xor(v, 1);
            packed[r] = packh2(v, p);
        }
        if ((c & 1) == 0) {
            #pragma unroll
            for (int q = 0; q < 4; q++) {
                uint4 u;
                u.x = packed[q * 4 + 0]; u.y = packed[q * 4 + 1];
                u.z = packed[q * 4 + 2]; u.w = packed[q * 4 + 3];
                *(uint4*)&eapk[c >> 1][g * 16 + q * 4] = u;
            }
        }
    }
    __syncthreads();

    if (tid < G3) {
        const int c = tid;
        float acc[GI_ROWS];
        const float bv = b_ih[c];
        #pragma unroll
        for (int r = 0; r < GI_ROWS; r++) acc[r] = bv;
        for (int k2 = 0; k2 < K2IH; k2++) {
            uint32 w = Wih_pk[k2 * G3 + c];
            #pragma unroll
            for (int q = 0; q < 8; q++) {
                const uint4 e4 = *(const uint4*)&eapk[k2][q * 4];
                acc[q * 4 + 0] = dot2f(w, e4.x, acc[q * 4 + 0]);
                acc[q * 4 + 1] = dot2f(w, e4.y, acc[q * 4 + 1]);
                acc[q * 4 + 2] = dot2f(w, e4.z, acc[q * 4 + 2]);
                acc[q * 4 + 3] = dot2f(w, e4.w, acc[q * 4 + 3]);
            }
        }
        // pack f16 pairs over c (lane parity == c parity), write u32
        uint32 pk[GI_ROWS];
        #pragma unroll
        for (int r = 0; r < GI_ROWS; r++) {
            float v = acc[r];
            float p = __shfl_xor(v, 1);
            pk[r] = packh2(v, p);
        }
        if ((c & 1) == 0) {
            #pragma unroll
            for (int r = 0; r < GI_ROWS; r++)
                gi_pk[(size_t)(rel0 + r) * 300 + (c >> 1)] = pk[r];
        }
    }
}

// ---------- phase B: MFMA GRU recurrence. 32 blocks x 16 batch rows, 8 waves ----------
#define RT_THREADS 512
#define RT_ROWS 16
#define NT 38        // 608/16 col tiles
#define KT_ 7        // 224/32 K tiles
#define HSTR 232     // h_lds row stride in f16 (200 + pad24 + bankskew)
#define GHSTR 612    // gh_lds row stride in f32
#define ITG 4        // gate iterations: 16*100 pairs / 512

__global__ __launch_bounds__(RT_THREADS, 2)
void recur4_kernel(const uint32* __restrict__ gi_pk, const uint32* __restrict__ WhhT_pk,
                   const float* __restrict__ b_hh, const float* __restrict__ in_state,
                   const unsigned char* __restrict__ reset_raw, const int* __restrict__ flags,
                   float* __restrict__ out_states, float* __restrict__ h_buf,
                   int t0, int t1, int first)
{
    __shared__ _Float16 h_lds[RT_ROWS * HSTR];   // 7424 B, A-operand layout [row][k]
    __shared__ float    gh_lds[RT_ROWS * GHSTR]; // 39168 B
    __shared__ float    rst_lds[RT_ROWS];

    const int tid  = threadIdx.x;
    const int lane = tid & 63;
    const int wv   = tid >> 6;
    const int bg0  = blockIdx.x * RT_ROWS;
    const int mode = flags[0];
    uint32* h32 = (uint32*)h_lds;

    // --- B fragments resident in VGPRs: wave wv owns col-tiles {wv + 8i} ---
    f16x8 bfr[5][KT_];
    float bcol[5];
    #pragma unroll
    for (int i = 0; i < 5; ++i) {
        int ct  = wv + 8 * i;
        int col = ct * 16 + (lane & 15);
        bcol[i] = (ct < NT && col < G3) ? b_hh[col] : 0.f;
        #pragma unroll
        for (int kt = 0; kt < KT_; ++kt) {
            if (ct < NT) {
                int k2b = kt * 16 + (lane >> 4) * 4;
                bfr[i][kt] = *(const f16x8*)&WhhT_pk[col * 112 + k2b];
            } else {
                bfr[i][kt] = f16x8{0, 0, 0, 0, 0, 0, 0, 0};
            }
        }
    }

    // --- h init: thread owns ITG (row, m-pair) units; h_old stays f32 in regs ---
    float hold[ITG][2];
    #pragma unroll
    for (int it = 0; it < ITG; ++it) {
        int u2 = it * RT_THREADS + tid;
        if (u2 < RT_ROWS * 100) {
            int row = u2 / 100, mp = u2 % 100, m = mp * 2;
            float a, b;
            if (first) {
                const float2 v = *(const float2*)&in_state[(size_t)(bg0 + row) * MEM + m];
                a = v.x; b = v.y;
                if (resetval(reset_raw, mode, bg0 + row)) { a = 0.f; b = 0.f; }
            } else {
                const float2 v = *(const float2*)&h_buf[(size_t)(bg0 + row) * MEM + m];
                a = v.x; b = v.y;
            }
            hold[it][0] = a; hold[it][1] = b;
            h32[row * 116 + mp] = packh2(a, b);
        }
    }
    if (tid < 256) {                        // zero the K-pad region [200,232)
        int row = tid >> 4, o = tid & 15;
        h32[row * 116 + 100 + o] = 0;
    }
    __syncthreads();

    for (int t = t0; t < t1; ++t) {
        // prefetch this step's gi (packed f16 pairs) -> regs; hides under MFMA+barrier
        uint32 pre[ITG][3];
        const size_t base32 = ((size_t)(t - t0) * B_ + bg0) * 300;
        #pragma unroll
        for (int it = 0; it < ITG; ++it) {
            int u2 = it * RT_THREADS + tid;
            if (u2 < RT_ROWS * 100) {
                int row = u2 / 100, mp = u2 % 100;
                pre[it][0] = gi_pk[base32 + row * 300 + mp];
                pre[it][1] = gi_pk[base32 + row * 300 + 100 + mp];
                pre[it][2] = gi_pk[base32 + row * 300 + 200 + mp];
            }
        }

        // A fragments: lane -> row = lane&15, k chunk = (lane>>4)*8 within K-tile
        f16x8 afr[KT_];
        #pragma unroll
        for (int kt = 0; kt < KT_; ++kt)
            afr[kt] = *(const f16x8*)&h_lds[(lane & 15) * HSTR + kt * 32 + (lane >> 4) * 8];

        // stage next-step reset flags
        if (tid < RT_ROWS) {
            int tt = t + 1;
            rst_lds[tid] = (tt < T_ && resetval(reset_raw, mode, tt * B_ + bg0 + tid)) ? 1.f : 0.f;
        }

        // MFMA: gh = h @ W_hh + b_hh
        #pragma unroll
        for (int i = 0; i < 5; ++i) {
            int ct = wv + 8 * i;
            if (ct >= NT) break;
            f32x4 acc = {bcol[i], bcol[i], bcol[i], bcol[i]};
            #pragma unroll
            for (int kt = 0; kt < KT_; ++kt)
                acc = __builtin_amdgcn_mfma_f32_16x16x32_f16(afr[kt], bfr[i][kt], acc, 0, 0, 0);
            int col = ct * 16 + (lane & 15);
            if (col < G3) {
                int r0 = (lane >> 4) * 4;   // C/D: col=lane&15, row=(lane>>4)*4+reg
                gh_lds[(r0 + 0) * GHSTR + col] = acc[0];
                gh_lds[(r0 + 1) * GHSTR + col] = acc[1];
                gh_lds[(r0 + 2) * GHSTR + col] = acc[2];
                gh_lds[(r0 + 3) * GHSTR + col] = acc[3];
            }
        }
        __syncthreads();

        // gates + state update (each thread: ITG row/m-pair units)
        #pragma unroll
        for (int it = 0; it < ITG; ++it) {
            int u2 = it * RT_THREADS + tid;
            if (u2 < RT_ROWS * 100) {
                int row = u2 / 100, mp = u2 % 100, m = mp * 2;
                h2v g_r = __builtin_bit_cast(h2v, pre[it][0]);
                h2v g_z = __builtin_bit_cast(h2v, pre[it][1]);
                h2v g_n = __builtin_bit_cast(h2v, pre[it][2]);
                const float2 ghr = *(const float2*)&gh_lds[row * GHSTR + m];
                const float2 ghz = *(const float2*)&gh_lds[row * GHSTR + 200 + m];
                const float2 ghn = *(const float2*)&gh_lds[row * GHSTR + 400 + m];
                float hn0, hn1;
                {
                    float rg = sigmf((float)g_r.x + ghr.x);
                    float zg = sigmf((float)g_z.x + ghz.x);
                    float x  = (float)g_n.x + rg * ghn.x;
                    x = fminf(fmaxf(x, -30.f), 30.f);
                    float e2 = __expf(2.f * x);
                    float ng = (e2 - 1.f) / (e2 + 1.f);
                    hn0 = (1.f - zg) * ng + zg * hold[it][0];
                }
                {
                    float rg = sigmf((float)g_r.y + ghr.y);
                    float zg = sigmf((float)g_z.y + ghz.y);
                    float x  = (float)g_n.y + rg * ghn.y;
                    x = fminf(fmaxf(x, -30.f), 30.f);
                    float e2 = __expf(2.f * x);
                    float ng = (e2 - 1.f) / (e2 + 1.f);
                    hn1 = (1.f - zg) * ng + zg * hold[it][1];
                }
                *(float2*)&out_states[((size_t)t * B_ + (bg0 + row)) * MEM + m] = make_float2(hn0, hn1);
                if (rst_lds[row] != 0.f) { hn0 = 0.f; hn1 = 0.f; }
                hold[it][0] = hn0; hold[it][1] = hn1;
                h32[row * 116 + mp] = packh2(hn0, hn1);
            }
        }
        __syncthreads();
    }

    #pragma unroll
    for (int it = 0; it < ITG; ++it) {
        int u2 = it * RT_THREADS + tid;
        if (u2 < RT_ROWS * 100) {
            int row = u2 / 100, mp = u2 % 100, m = mp * 2;
            *(float2*)&h_buf[(size_t)(bg0 + row) * MEM + m] = make_float2(hold[it][0], hold[it][1]);
        }
    }
}

// ---------- phase C: post MLP over all states ----------
#define PC_THREADS 256
#define PC_ROWS 32

__global__ __launch_bounds__(PC_THREADS)
void post2_kernel(const float* __restrict__ states, const uint32* __restrict__ Wp1_pk,
                  const float* __restrict__ bp1, const uint32* __restrict__ Wp2_pk,
                  const float* __restrict__ bp2, float* __restrict__ posts)
{
    __shared__ __align__(16) uint32 hp[K2IH][RP];
    __shared__ __align__(16) uint32 mp[K2IH][RP];

    const int tid = threadIdx.x;
    const size_t rg0 = (size_t)blockIdx.x * PC_ROWS;

    for (int idx = tid; idx < PC_ROWS * K2IH; idx += PC_THREADS) {
        int r = idx / K2IH, k2 = idx % K2IH;
        const float2 v = *(const float2*)&states[(rg0 + r) * MEM + 2 * k2];
        hp[k2][r] = packh2(v.x, v.y);
    }
    __syncthreads();

    if (tid < MEM) {
        const int c = tid;
        float acc[PC_ROWS];
        const float bv = bp1[c];
        #pragma unroll
        for (int r = 0; r < PC_ROWS; r++) acc[r] = bv;
        for (int k2 = 0; k2 < K2IH; k2++) {
            uint32 w = Wp1_pk[k2 * MEM + c];
            #pragma unroll
            for (int q = 0; q < 8; q++) {
                const uint4 e4 = *(const uint4*)&hp[k2][q * 4];
                acc[q * 4 + 0] = dot2f(w, e4.x, acc[q * 4 + 0]);
                acc[q * 4 + 1] = dot2f(w, e4.y, acc[q * 4 + 1]);
                acc[q * 4 + 2] = dot2f(w, e4.z, acc[q * 4 + 2]);
                acc[q * 4 + 3] = dot2f(w, e4.w, acc[q * 4 + 3]);
            }
        }
        uint32 packed[PC_ROWS];
        #pragma unroll
        for (int r = 0; r < PC_ROWS; r++) {
            float v = eluf(acc[r]);
            float p = __shfl_xor(v, 1);
            packed[r] = packh2(v, p);
        }
        if ((c & 1) == 0) {
            #pragma unroll
            for (int q = 0; q < 8; q++) {
                uint4 u;
                u.x = packed[q * 4 + 0]; u.y = packed[q * 4 + 1];
                u.z = packed[q * 4 + 2]; u.w = packed[q * 4 + 3];
                *(uint4*)&mp[c >> 1][q * 4] = u;
            }
        }
    }
    __syncthreads();

    if (tid < 240) {
        const int c = tid % 60;
        const int q = tid / 60;
        float acc[8];
        const float bv = bp2[c];
        #pragma unroll
        for (int r = 0; r < 8; r++) acc[r] = bv;
        for (int k2 = 0; k2 < K2IH; k2++) {
            uint32 w = Wp2_pk[k2 * 60 + c];
            const uint4 a4 = *(const uint4*)&mp[k2][q * 8 + 0];
            const uint4 b4 = *(const uint4*)&mp[k2][q * 8 + 4];
            acc[0] = dot2f(w, a4.x, acc[0]);
            acc[1] = dot2f(w, a4.y, acc[1]);
            acc[2] = dot2f(w, a4.z, acc[2]);
            acc[3] = dot2f(w, a4.w, acc[3]);
            acc[4] = dot2f(w, b4.x, acc[4]);
            acc[5] = dot2f(w, b4.y, acc[5]);
            acc[6] = dot2f(w, b4.z, acc[6]);
            acc[7] = dot2f(w, b4.w, acc[7]);
        }
        #pragma unroll
        for (int r8 = 0; r8 < 8; r8++) {
            size_t rg = rg0 + q * 8 + r8;
            float v = acc[r8];
            posts[rg * 60 + c] = (c < 30) ? v : (splusf(v) + 0.1f);
        }
    }
}

// ---------- sample = mean + std*noise from posts[T-1] ----------
__global__ void sample_kernel(const float* __restrict__ posts_last,
                              const float* __restrict__ noise, float* __restrict__ out)
{
    int idx = blockIdx.x * blockDim.x + threadIdx.x;
    if (idx < B_ * STOCH) {
        int b = idx / STOCH, s = idx % STOCH;
        float mean = posts_last[b * 60 + s];
        float stdv = posts_last[b * 60 + 30 + s];
        out[idx] = mean + stdv * noise[idx];
    }
}

extern "C" void kernel_launch(void* const* d_in, const int* in_sizes, int n_in,
                              void* d_out, int out_size, void* d_ws, size_t ws_size,
                              hipStream_t stream)
{
    const float* embed   = (const float*)d_in[0];
    const float* action  = (const float*)d_in[1];
    const unsigned char* reset = (const unsigned char*)d_in[2];
    const float* in_state = (const float*)d_in[3];
    const float* noise   = (const float*)d_in[4];
    const float* W_ea = (const float*)d_in[5];
    const float* b_ea = (const float*)d_in[6];
    const float* W_ih = (const float*)d_in[7];
    const float* b_ih = (const float*)d_in[8];
    const float* W_hh = (const float*)d_in[9];
    const float* b_hh = (const float*)d_in[10];
    const float* Wp1  = (const float*)d_in[11];
    const float* bp1  = (const float*)d_in[12];
    const float* Wp2  = (const float*)d_in[13];
    const float* bp2  = (const float*)d_in[14];

    float* out_sample = (float*)d_out;
    float* out_states = out_sample + (size_t)B_ * STOCH;
    float* out_posts  = out_states + (size_t)T_ * B_ * MEM;

    char* ws = (char*)d_ws;
    size_t off = 0;
    int*    flags   = (int*)(ws + off);     off += 256;
    float*  h_buf   = (float*)(ws + off);   off += (size_t)B_ * MEM * 4;        // 409600
    uint32* Wea_pk  = (uint32*)(ws + off);  off += (size_t)K2EA * 200 * 4;      // 105600
    uint32* Wih_pk  = (uint32*)(ws + off);  off += (size_t)K2IH * G3 * 4;       // 240000
    uint32* WhhT_pk = (uint32*)(ws + off);  off += (size_t)608 * 112 * 4;       // 272384
    uint32* Wp1_pk  = (uint32*)(ws + off);  off += (size_t)K2IH * MEM * 4;      // 80000
    uint32* Wp2_pk  = (uint32*)(ws + off);  off += (size_t)K2IH * 60 * 4;       // 24000
    uint32* gi_buf  = (uint32*)(ws + off);

    const size_t per_t = (size_t)B_ * 300 * 4;   // packed f16 gi: 614400 B per timestep
    size_t avail = (ws_size > off) ? (ws_size - off) : 0;
    int maxT = (int)(avail / per_t);
    int chunkT = 1;
    while (chunkT * 2 <= maxT && chunkT < T_) chunkT *= 2;

    detect_kernel<<<1, 1024, 0, stream>>>(reset, T_ * B_, flags);
    pack_kernel<<<(K2EA * 200 + 255) / 256, 256, 0, stream>>>(W_ea, Wea_pk, EAIN, 200);
    pack_kernel<<<(K2IH * G3 + 255) / 256, 256, 0, stream>>>(W_ih, Wih_pk, HIDD, G3);
    packWT_kernel<<<(608 * 112 + 255) / 256, 256, 0, stream>>>(W_hh, WhhT_pk);
    pack_kernel<<<(K2IH * MEM + 255) / 256, 256, 0, stream>>>(Wp1, Wp1_pk, MEM, MEM);
    pack_kernel<<<(K2IH * 60 + 255) / 256, 256, 0, stream>>>(Wp2, Wp2_pk, MEM, 60);

    for (int t0 = 0; t0 < T_; t0 += chunkT) {
        int rows = chunkT * B_;
        gi2_kernel<<<rows / GI_ROWS, GI_THREADS, 0, stream>>>(
            embed, action, Wea_pk, b_ea, Wih_pk, b_ih, gi_buf, t0 * B_);
        recur4_kernel<<<B_ / RT_ROWS, RT_THREADS, 0, stream>>>(
            gi_buf, WhhT_pk, b_hh, in_state, reset, flags,
            out_states, h_buf, t0, t0 + chunkT, (t0 == 0) ? 1 : 0);
    }

    post2_kernel<<<(T_ * B_) / PC_ROWS, PC_THREADS, 0, stream>>>(
        out_states, Wp1_pk, bp1, Wp2_pk, bp2, out_posts);

    sample_kernel<<<(B_ * STOCH + 255) / 256, 256, 0, stream>>>(
        out_posts + (size_t)(T_ - 1) * B_ * 60, noise, out_sample);
}

// Round 6
// 920.191 us; speedup vs baseline: 2.7269x; 1.6140x over previous
//
#include <hip/hip_runtime.h>
#include <math.h>

#define EMBED 256
#define ACTD  7
#define MEM   200
#define STOCH 30
#define T_    256
#define B_    512
#define EAIN  263
#define G3    600

typedef unsigned int uint32;
typedef _Float16 h2v   __attribute__((ext_vector_type(2)));
typedef _Float16 f16x8 __attribute__((ext_vector_type(8)));
typedef float    f32x4 __attribute__((ext_vector_type(4)));

// ---------- math helpers ----------
__device__ __forceinline__ float eluf(float x)  { return x > 0.f ? x : expm1f(x); }
__device__ __forceinline__ float sigmf(float x) { return 1.f / (1.f + __expf(-x)); }
__device__ __forceinline__ float splusf(float x){ return fmaxf(x, 0.f) + log1pf(__expf(-fabsf(x))); }

__device__ __forceinline__ uint32 packh2(float a, float b) {
#if __has_builtin(__builtin_amdgcn_cvt_pkrtz)
    auto h = __builtin_amdgcn_cvt_pkrtz(a, b);
    return __builtin_bit_cast(uint32, h);
#else
    h2v h; h.x = (_Float16)a; h.y = (_Float16)b;
    return __builtin_bit_cast(uint32, h);
#endif
}

// ---------- reset dtype detection ----------
__global__ void detect_kernel(const unsigned char* __restrict__ p, int n, int* __restrict__ flags)
{
    __shared__ int s_mis, s_gt1;
    if (threadIdx.x == 0) { s_mis = 0; s_gt1 = 0; }
    __syncthreads();
    int mis = 0, gt1 = 0;
    for (int i = threadIdx.x; i < n; i += blockDim.x) {
        unsigned char v = p[i];
        if (v) {
            if (i & 3) mis = 1;
            if (v > 1) gt1 = 1;
        }
    }
    if (mis) atomicOr(&s_mis, 1);
    if (gt1) atomicOr(&s_gt1, 1);
    __syncthreads();
    if (threadIdx.x == 0) flags[0] = s_mis ? (s_gt1 ? 2 : 1) : 0;
}

__device__ __forceinline__ bool resetval(const unsigned char* __restrict__ p, int mode, int idx)
{
    if (mode == 0) return ((const int*)p)[idx] != 0;
    if (mode == 1) return p[idx] != 0;
    return ((const float*)p)[idx] != 0.f;
}

// ---------- generic transpose-pack: src[K][C] f32 -> dst[Cpad][K2pad] u32 (f16 pair over k) ----------
__global__ void packT_kernel(const float* __restrict__ src, uint32* __restrict__ dst,
                             int K, int C, int Cpad, int K2pad)
{
    int idx = blockIdx.x * blockDim.x + threadIdx.x;
    if (idx < Cpad * K2pad) {
        int c = idx / K2pad, k2 = idx % K2pad;
        float a = (c < C && 2 * k2     < K) ? src[(size_t)(2 * k2)     * C + c] : 0.f;
        float b = (c < C && 2 * k2 + 1 < K) ? src[(size_t)(2 * k2 + 1) * C + c] : 0.f;
        dst[idx] = packh2(a, b);
    }
}

// ---------- phase A: gi = elu([e,a]@W_ea+b_ea)@W_ih + b_ih, MFMA, 32 rows/block ----------
// A-frag: row=lane&15, k=kt*32+(lane>>4)*8+j   (validated by recur4)
// B-frag: col=lane&15 (of tile), k2=kt*16+(lane>>4)*4.. (validated by recur4)
// C/D   : col=lane&15, row=(lane>>4)*4+j       (validated by recur4)
#define GI3_T 512

__global__ __launch_bounds__(GI3_T)
void gi3_kernel(const float* __restrict__ embed, const float* __restrict__ action,
                const uint32* __restrict__ WeaT, const float* __restrict__ b_ea,
                const uint32* __restrict__ WihT, const float* __restrict__ b_ih,
                uint32* __restrict__ gi_pk, int row_base)
{
    __shared__ __align__(16) uint32 Epk[32 * 148];   // E f16 [32 rows][296 stride], K_ea pad 288
    __shared__ __align__(16) uint32 eapk[32 * 116];  // ea f16 [32 rows][232 stride], K pad 224

    const int tid = threadIdx.x, lane = tid & 63, wv = tid >> 6;
    const int lo = lane & 15, hi = lane >> 4, r0 = hi * 4;
    const int rel0 = blockIdx.x * 32;
    const int rg0  = row_base + rel0;

    // stage E = concat(embed, action) as f16 pairs
    for (int idx = tid; idx < 32 * 144; idx += GI3_T) {
        int r = idx / 144, k2 = idx % 144;
        size_t rg = (size_t)(rg0 + r);
        float a = 0.f, b = 0.f;
        if (k2 < 128) {
            const float2 v = *(const float2*)&embed[rg * EMBED + 2 * k2];
            a = v.x; b = v.y;
        } else if (k2 < 132) {
            int k = 2 * k2 - EMBED;
            a = action[rg * ACTD + k];
            b = (k + 1 < ACTD) ? action[rg * ACTD + k + 1] : 0.f;
        }
        Epk[r * 148 + k2] = packh2(a, b);
    }
    { int r = tid >> 4, o = tid & 15; eapk[r * 116 + 100 + o] = 0; }  // zero K-pad [200,232)
    __syncthreads();

    const _Float16* E16  = (const _Float16*)Epk;
    _Float16*       ea16 = (_Float16*)eapk;

    // ---- ea GEMM: [32 x 288] @ [288 x 208] ----
    f16x8 afr[2][9];
    #pragma unroll
    for (int mt = 0; mt < 2; mt++)
        #pragma unroll
        for (int kt = 0; kt < 9; kt++)
            afr[mt][kt] = *(const f16x8*)&E16[(mt * 16 + lo) * 296 + kt * 32 + hi * 8];

    for (int nt = wv; nt < 13; nt += 8) {
        int col = nt * 16 + lo;
        float bv = (col < 200) ? b_ea[col] : 0.f;
        f16x8 wb[9];
        #pragma unroll
        for (int kt = 0; kt < 9; kt++)
            wb[kt] = *(const f16x8*)&WeaT[col * 144 + kt * 16 + hi * 4];
        #pragma unroll
        for (int mt = 0; mt < 2; mt++) {
            f32x4 acc = {bv, bv, bv, bv};
            #pragma unroll
            for (int kt = 0; kt < 9; kt++)
                acc = __builtin_amdgcn_mfma_f32_16x16x32_f16(afr[mt][kt], wb[kt], acc, 0, 0, 0);
            #pragma unroll
            for (int j = 0; j < 4; j++)
                ea16[(mt * 16 + r0 + j) * 232 + col] = (_Float16)eluf(acc[j]);
        }
    }
    __syncthreads();

    // ---- gi GEMM: [32 x 224] @ [224 x 608] ----
    f16x8 afr2[2][7];
    #pragma unroll
    for (int mt = 0; mt < 2; mt++)
        #pragma unroll
        for (int kt = 0; kt < 7; kt++)
            afr2[mt][kt] = *(const f16x8*)&ea16[(mt * 16 + lo) * 232 + kt * 32 + hi * 8];

    for (int nt = wv; nt < 38; nt += 8) {
        int col = nt * 16 + lo;
        float bv = (col < G3) ? b_ih[col] : 0.f;
        f16x8 wb[7];
        #pragma unroll
        for (int kt = 0; kt < 7; kt++)
            wb[kt] = *(const f16x8*)&WihT[col * 112 + kt * 16 + hi * 4];
        #pragma unroll
        for (int mt = 0; mt < 2; mt++) {
            f32x4 acc = {bv, bv, bv, bv};
            #pragma unroll
            for (int kt = 0; kt < 7; kt++)
                acc = __builtin_amdgcn_mfma_f32_16x16x32_f16(afr2[mt][kt], wb[kt], acc, 0, 0, 0);
            #pragma unroll
            for (int j = 0; j < 4; j++) {
                float v = acc[j];
                float p = __shfl_xor(v, 1);            // pair adjacent cols
                if (((lane & 1) == 0) && col < G3)
                    gi_pk[(size_t)(rel0 + mt * 16 + r0 + j) * 300 + (col >> 1)] = packh2(v, p);
            }
        }
    }
}

// ---------- phase B: MFMA GRU recurrence, 64 blocks x 8 batch rows, prefetch t+1 ----------
#define RR 8

__global__ __launch_bounds__(512, 2)
void recur5_kernel(const uint32* __restrict__ gi_pk, const uint32* __restrict__ WhhT,
                   const float* __restrict__ b_hh, const float* __restrict__ in_state,
                   const unsigned char* __restrict__ reset_raw, const int* __restrict__ flags,
                   float* __restrict__ out_states, float* __restrict__ h_buf,
                   int t0, int t1, int first)
{
    __shared__ _Float16 h_lds[16 * 232];   // rows 8-15 zero pad (MFMA M=16)
    __shared__ float    gh_lds[RR * 612];
    __shared__ float    rst_lds[RR];

    const int tid = threadIdx.x, lane = tid & 63, wv = tid >> 6;
    const int lo = lane & 15, hi = lane >> 4, r0c = hi * 4;
    const int bg0 = blockIdx.x * RR;
    const int mode = flags[0];
    uint32* h32 = (uint32*)h_lds;

    // B fragments resident: wave wv owns col-tiles {wv+8i}
    f16x8 bfr[5][7];
    float bcol[5];
    #pragma unroll
    for (int i = 0; i < 5; ++i) {
        int ct  = wv + 8 * i;
        int col = ct * 16 + lo;
        bcol[i] = (ct < 38 && col < G3) ? b_hh[col] : 0.f;
        #pragma unroll
        for (int kt = 0; kt < 7; ++kt)
            bfr[i][kt] = (ct < 38) ? *(const f16x8*)&WhhT[col * 112 + kt * 16 + hi * 4]
                                   : f16x8{0, 0, 0, 0, 0, 0, 0, 0};
    }

    // zero pads: rows 0-7 k-pad [100,116) u32, rows 8-15 entirely
    for (int idx = tid; idx < 1056; idx += 512) {
        int r, o;
        if (idx < 128) { r = idx >> 4; o = 100 + (idx & 15); }
        else { int j = idx - 128; r = 8 + j / 116; o = j % 116; }
        h32[r * 116 + o] = 0;
    }

    float hold[2][2];
    #pragma unroll
    for (int it = 0; it < 2; ++it) {
        int u2 = it * 512 + tid;
        if (u2 < RR * 100) {
            int row = u2 / 100, mp = u2 % 100, m = mp * 2;
            float a, b;
            if (first) {
                const float2 v = *(const float2*)&in_state[(size_t)(bg0 + row) * MEM + m];
                a = v.x; b = v.y;
                if (resetval(reset_raw, mode, bg0 + row)) { a = 0.f; b = 0.f; }
            } else {
                const float2 v = *(const float2*)&h_buf[(size_t)(bg0 + row) * MEM + m];
                a = v.x; b = v.y;
            }
            hold[it][0] = a; hold[it][1] = b;
            h32[row * 116 + mp] = packh2(a, b);
        }
    }
    __syncthreads();

    uint32 pcur[2][3], pnxt[2][3];
    {   // prologue prefetch for t0
        const size_t base32 = (size_t)bg0 * 300;
        #pragma unroll
        for (int it = 0; it < 2; ++it) {
            int u2 = it * 512 + tid;
            if (u2 < RR * 100) {
                int row = u2 / 100, mp = u2 % 100;
                pcur[it][0] = gi_pk[base32 + row * 300 + mp];
                pcur[it][1] = gi_pk[base32 + row * 300 + 100 + mp];
                pcur[it][2] = gi_pk[base32 + row * 300 + 200 + mp];
            }
        }
    }

    for (int t = t0; t < t1; ++t) {
        // issue NEXT step's gi loads now; waited on only after the gate phase
        if (t + 1 < t1) {
            const size_t base32 = ((size_t)(t + 1 - t0) * B_ + bg0) * 300;
            #pragma unroll
            for (int it = 0; it < 2; ++it) {
                int u2 = it * 512 + tid;
                if (u2 < RR * 100) {
                    int row = u2 / 100, mp = u2 % 100;
                    pnxt[it][0] = gi_pk[base32 + row * 300 + mp];
                    pnxt[it][1] = gi_pk[base32 + row * 300 + 100 + mp];
                    pnxt[it][2] = gi_pk[base32 + row * 300 + 200 + mp];
                }
            }
        }

        f16x8 afr[7];
        #pragma unroll
        for (int kt = 0; kt < 7; ++kt)
            afr[kt] = *(const f16x8*)&h_lds[lo * 232 + kt * 32 + hi * 8];

        if (tid < RR) {
            int tt = t + 1;
            rst_lds[tid] = (tt < T_ && resetval(reset_raw, mode, tt * B_ + bg0 + tid)) ? 1.f : 0.f;
        }

        #pragma unroll
        for (int i = 0; i < 5; ++i) {
            int ct = wv + 8 * i;
            if (ct >= 38) break;
            f32x4 acc = {bcol[i], bcol[i], bcol[i], bcol[i]};
            #pragma unroll
            for (int kt = 0; kt < 7; ++kt)
                acc = __builtin_amdgcn_mfma_f32_16x16x32_f16(afr[kt], bfr[i][kt], acc, 0, 0, 0);
            int col = ct * 16 + lo;
            if (col < G3 && r0c < RR) {           // only valid rows 0-7 stored
                gh_lds[(r0c + 0) * 612 + col] = acc[0];
                gh_lds[(r0c + 1) * 612 + col] = acc[1];
                gh_lds[(r0c + 2) * 612 + col] = acc[2];
                gh_lds[(r0c + 3) * 612 + col] = acc[3];
            }
        }
        __syncthreads();

        #pragma unroll
        for (int it = 0; it < 2; ++it) {
            int u2 = it * 512 + tid;
            if (u2 < RR * 100) {
                int row = u2 / 100, mp = u2 % 100, m = mp * 2;
                h2v g_r = __builtin_bit_cast(h2v, pcur[it][0]);
                h2v g_z = __builtin_bit_cast(h2v, pcur[it][1]);
                h2v g_n = __builtin_bit_cast(h2v, pcur[it][2]);
                const float2 ghr = *(const float2*)&gh_lds[row * 612 + m];
                const float2 ghz = *(const float2*)&gh_lds[row * 612 + 200 + m];
                const float2 ghn = *(const float2*)&gh_lds[row * 612 + 400 + m];
                float hn0, hn1;
                {
                    float rg = sigmf((float)g_r.x + ghr.x);
                    float zg = sigmf((float)g_z.x + ghz.x);
                    float x  = (float)g_n.x + rg * ghn.x;
                    x = fminf(fmaxf(x, -30.f), 30.f);
                    float e2 = __expf(2.f * x);
                    float ng = (e2 - 1.f) / (e2 + 1.f);
                    hn0 = (1.f - zg) * ng + zg * hold[it][0];
                }
                {
                    float rg = sigmf((float)g_r.y + ghr.y);
                    float zg = sigmf((float)g_z.y + ghz.y);
                    float x  = (float)g_n.y + rg * ghn.y;
                    x = fminf(fmaxf(x, -30.f), 30.f);
                    float e2 = __expf(2.f * x);
                    float ng = (e2 - 1.f) / (e2 + 1.f);
                    hn1 = (1.f - zg) * ng + zg * hold[it][1];
                }
                *(float2*)&out_states[((size_t)t * B_ + (bg0 + row)) * MEM + m] = make_float2(hn0, hn1);
                if (rst_lds[row] != 0.f) { hn0 = 0.f; hn1 = 0.f; }
                hold[it][0] = hn0; hold[it][1] = hn1;
                h32[row * 116 + mp] = packh2(hn0, hn1);
            }
        }
        // rotate prefetch (forces the vmcnt wait here, after gates)
        #pragma unroll
        for (int it = 0; it < 2; ++it) {
            pcur[it][0] = pnxt[it][0]; pcur[it][1] = pnxt[it][1]; pcur[it][2] = pnxt[it][2];
        }
        __syncthreads();
    }

    #pragma unroll
    for (int it = 0; it < 2; ++it) {
        int u2 = it * 512 + tid;
        if (u2 < RR * 100) {
            int row = u2 / 100, mp = u2 % 100, m = mp * 2;
            *(float2*)&h_buf[(size_t)(bg0 + row) * MEM + m] = make_float2(hold[it][0], hold[it][1]);
        }
    }
}

// ---------- phase C: post MLP, MFMA, 32 rows/block ----------
__global__ __launch_bounds__(512)
void post3_kernel(const float* __restrict__ states, const uint32* __restrict__ Wp1T,
                  const float* __restrict__ bp1, const uint32* __restrict__ Wp2T,
                  const float* __restrict__ bp2, float* __restrict__ posts)
{
    __shared__ __align__(16) uint32 hp[32 * 116];
    __shared__ __align__(16) uint32 mpk[32 * 116];

    const int tid = threadIdx.x, lane = tid & 63, wv = tid >> 6;
    const int lo = lane & 15, hi = lane >> 4, r0 = hi * 4;
    const size_t rg0 = (size_t)blockIdx.x * 32;

    { int r = tid >> 4, o = tid & 15; hp[r * 116 + 100 + o] = 0; mpk[r * 116 + 100 + o] = 0; }
    for (int idx = tid; idx < 32 * 100; idx += 512) {
        int r = idx / 100, k2 = idx % 100;
        const float2 v = *(const float2*)&states[(rg0 + r) * MEM + 2 * k2];
        hp[r * 116 + k2] = packh2(v.x, v.y);
    }
    __syncthreads();

    const _Float16* h16 = (const _Float16*)hp;
    _Float16*       m16 = (_Float16*)mpk;

    // mid = elu(h @ Wp1 + bp1): [32 x 224] @ [224 x 208]
    f16x8 afr[2][7];
    #pragma unroll
    for (int mt = 0; mt < 2; mt++)
        #pragma unroll
        for (int kt = 0; kt < 7; kt++)
            afr[mt][kt] = *(const f16x8*)&h16[(mt * 16 + lo) * 232 + kt * 32 + hi * 8];

    for (int nt = wv; nt < 13; nt += 8) {
        int col = nt * 16 + lo;
        float bv = (col < MEM) ? bp1[col] : 0.f;
        f16x8 wb[7];
        #pragma unroll
        for (int kt = 0; kt < 7; kt++)
            wb[kt] = *(const f16x8*)&Wp1T[col * 112 + kt * 16 + hi * 4];
        #pragma unroll
        for (int mt = 0; mt < 2; mt++) {
            f32x4 acc = {bv, bv, bv, bv};
            #pragma unroll
            for (int kt = 0; kt < 7; kt++)
                acc = __builtin_amdgcn_mfma_f32_16x16x32_f16(afr[mt][kt], wb[kt], acc, 0, 0, 0);
            #pragma unroll
            for (int j = 0; j < 4; j++)
                m16[(mt * 16 + r0 + j) * 232 + col] = (_Float16)eluf(acc[j]);
        }
    }
    __syncthreads();

    // post = mid @ Wp2 + bp2: [32 x 224] @ [224 x 64]; wave -> (nt = wv&3, mt = wv>>2)
    {
        int nt = wv & 3, mt = wv >> 2;
        int col = nt * 16 + lo;
        float bv = (col < 60) ? bp2[col] : 0.f;
        f16x8 a2[7], wb[7];
        #pragma unroll
        for (int kt = 0; kt < 7; kt++) {
            a2[kt] = *(const f16x8*)&m16[(mt * 16 + lo) * 232 + kt * 32 + hi * 8];
            wb[kt] = *(const f16x8*)&Wp2T[col * 112 + kt * 16 + hi * 4];
        }
        f32x4 acc = {bv, bv, bv, bv};
        #pragma unroll
        for (int kt = 0; kt < 7; kt++)
            acc = __builtin_amdgcn_mfma_f32_16x16x32_f16(a2[kt], wb[kt], acc, 0, 0, 0);
        if (col < 60) {
            #pragma unroll
            for (int j = 0; j < 4; j++) {
                float v = acc[j];
                posts[(rg0 + mt * 16 + r0 + j) * 60 + col] = (col < 30) ? v : (splusf(v) + 0.1f);
            }
        }
    }
}

// ---------- sample = mean + std*noise from posts[T-1] ----------
__global__ void sample_kernel(const float* __restrict__ posts_last,
                              const float* __restrict__ noise, float* __restrict__ out)
{
    int idx = blockIdx.x * blockDim.x + threadIdx.x;
    if (idx < B_ * STOCH) {
        int b = idx / STOCH, s = idx % STOCH;
        float mean = posts_last[b * 60 + s];
        float stdv = posts_last[b * 60 + 30 + s];
        out[idx] = mean + stdv * noise[idx];
    }
}

extern "C" void kernel_launch(void* const* d_in, const int* in_sizes, int n_in,
                              void* d_out, int out_size, void* d_ws, size_t ws_size,
                              hipStream_t stream)
{
    const float* embed   = (const float*)d_in[0];
    const float* action  = (const float*)d_in[1];
    const unsigned char* reset = (const unsigned char*)d_in[2];
    const float* in_state = (const float*)d_in[3];
    const float* noise   = (const float*)d_in[4];
    const float* W_ea = (const float*)d_in[5];
    const float* b_ea = (const float*)d_in[6];
    const float* W_ih = (const float*)d_in[7];
    const float* b_ih = (const float*)d_in[8];
    const float* W_hh = (const float*)d_in[9];
    const float* b_hh = (const float*)d_in[10];
    const float* Wp1  = (const float*)d_in[11];
    const float* bp1  = (const float*)d_in[12];
    const float* Wp2  = (const float*)d_in[13];
    const float* bp2  = (const float*)d_in[14];

    float* out_sample = (float*)d_out;
    float* out_states = out_sample + (size_t)B_ * STOCH;
    float* out_posts  = out_states + (size_t)T_ * B_ * MEM;

    char* ws = (char*)d_ws;
    size_t off = 0;
    int*    flags = (int*)(ws + off);    off += 256;
    float*  h_buf = (float*)(ws + off);  off += (size_t)B_ * MEM * 4;     // 409600
    uint32* WeaT  = (uint32*)(ws + off); off += (size_t)208 * 144 * 4;    // 119808
    uint32* WihT  = (uint32*)(ws + off); off += (size_t)608 * 112 * 4;    // 272384
    uint32* WhhT  = (uint32*)(ws + off); off += (size_t)608 * 112 * 4;    // 272384
    uint32* Wp1T  = (uint32*)(ws + off); off += (size_t)208 * 112 * 4;    // 93184
    uint32* Wp2T  = (uint32*)(ws + off); off += (size_t)64 * 112 * 4;     // 28672
    uint32* gi_buf = (uint32*)(ws + off);

    const size_t per_t = (size_t)B_ * 300 * 4;   // packed f16 gi per timestep
    size_t avail = (ws_size > off) ? (ws_size - off) : 0;
    int maxT = (int)(avail / per_t);
    int chunkT = 1;
    while (chunkT * 2 <= maxT && chunkT < T_) chunkT *= 2;

    detect_kernel<<<1, 1024, 0, stream>>>(reset, T_ * B_, flags);
    packT_kernel<<<(208 * 144 + 255) / 256, 256, 0, stream>>>(W_ea, WeaT, EAIN, 200, 208, 144);
    packT_kernel<<<(608 * 112 + 255) / 256, 256, 0, stream>>>(W_ih, WihT, 200, 600, 608, 112);
    packT_kernel<<<(608 * 112 + 255) / 256, 256, 0, stream>>>(W_hh, WhhT, 200, 600, 608, 112);
    packT_kernel<<<(208 * 112 + 255) / 256, 256, 0, stream>>>(Wp1, Wp1T, 200, 200, 208, 112);
    packT_kernel<<<(64 * 112 + 255) / 256, 256, 0, stream>>>(Wp2, Wp2T, 200, 60, 64, 112);

    for (int t0 = 0; t0 < T_; t0 += chunkT) {
        int rows = chunkT * B_;
        gi3_kernel<<<rows / 32, GI3_T, 0, stream>>>(
            embed, action, WeaT, b_ea, WihT, b_ih, gi_buf, t0 * B_);
        recur5_kernel<<<B_ / RR, 512, 0, stream>>>(
            gi_buf, WhhT, b_hh, in_state, reset, flags,
            out_states, h_buf, t0, t0 + chunkT, (t0 == 0) ? 1 : 0);
    }

    post3_kernel<<<(T_ * B_) / 32, 512, 0, stream>>>(
        out_states, Wp1T, bp1, Wp2T, bp2, out_posts);

    sample_kernel<<<(B_ * STOCH + 255) / 256, 256, 0, stream>>>(
        out_posts + (size_t)(T_ - 1) * B_ * 60, noise, out_sample);
}